// Round 9
// baseline (112.493 us; speedup 1.0000x reference)
//
#include <hip/hip_runtime.h>

#define B_   512
#define F_   2048
#define K_   64
#define D_   16
#define N_   1024
#define OUTW (F_+K_)    // 2112
#define LOG2E 1.44269504088896340736f

typedef __attribute__((ext_vector_type(8))) short short8;
typedef __attribute__((ext_vector_type(4))) float f32x4;

__device__ __forceinline__ ushort f2bf(float f) {
    union { float f; unsigned u; } un; un.f = f;
    unsigned u = un.u;
    u += 0x7FFF + ((u >> 16) & 1);   // RNE
    return (ushort)(u >> 16);
}

// exp2 via raw v_exp_f32, with negation folded into the input modifier
__device__ __forceinline__ float exp2_neg(float x) {
    float r;
    asm("v_exp_f32 %0, -%1" : "=v"(r) : "v"(x));
    return r;
}

// ---- fused: out[b][0:2048] = x  AND  xb = bf16(x * log2e) ----
__global__ __launch_bounds__(256) void convert_x_kernel(const float* __restrict__ x,
                                                        float* __restrict__ out,
                                                        ushort* __restrict__ xb) {
    const int i = blockIdx.x * 256 + threadIdx.x;     // 262144 float4's
    float4 v = ((const float4*)x)[i];
    const int b = i >> 9, c = i & 511;
    ((float4*)out)[b * (OUTW / 4) + c] = v;
    ushort4 u = make_ushort4(f2bf(v.x * LOG2E), f2bf(v.y * LOG2E),
                             f2bf(v.z * LOG2E), f2bf(v.w * LOG2E));
    ((ushort4*)xb)[i] = u;
}

// ---- Wt[n][f] = bf16(W[f][n]) : LDS-tiled transpose ----
__global__ __launch_bounds__(256) void convert_wt_kernel(const float* __restrict__ w,
                                                         ushort* __restrict__ wt) {
    __shared__ float t[32][33];
    const int f0 = blockIdx.x * 32;    // 64
    const int n0 = blockIdx.y * 32;    // 32
    const int tid = threadIdx.x;
    const int r = tid >> 3;            // 0..31
    const int c4 = (tid & 7) * 4;      // 0..28
    float4 v = *(const float4*)(w + (size_t)(f0 + r) * N_ + n0 + c4);
    t[r][c4 + 0] = v.x; t[r][c4 + 1] = v.y; t[r][c4 + 2] = v.z; t[r][c4 + 3] = v.w;
    __syncthreads();
    ushort4 u = make_ushort4(f2bf(t[c4 + 0][r]), f2bf(t[c4 + 1][r]),
                             f2bf(t[c4 + 2][r]), f2bf(t[c4 + 3][r]));
    *(ushort4*)(wt + (size_t)(n0 + r) * F_ + f0 + c4) = u;
}

// ---- MFMA GEMM: act[k][b][d] = sum_f xb[b][f] * wt[n][f],  n = k*16+d ----
// 64x32 tile, grid (8,32)=256 blocks, 4 waves (2x2), full K, direct stores (no atomics).
__global__ __launch_bounds__(256) void gemm_mfma_kernel(const ushort* __restrict__ xb,
                                                        const ushort* __restrict__ wt,
                                                        float* __restrict__ act) {
    const int bm0 = blockIdx.x * 64;   // 8
    const int bn0 = blockIdx.y * 32;   // 32
    const int tid = threadIdx.x;
    const int l   = tid & 63;
    const int w   = tid >> 6;
    const int mw  = (w >> 1) * 32;     // 0,32
    const int nw  = (w & 1) * 16;      // 0,16
    const int lr  = l & 15;
    const int lk  = (l >> 4) * 8;

    const ushort* pa0 = xb + (size_t)(bm0 + mw + lr) * F_ + lk;
    const ushort* pa1 = pa0 + 16 * F_;
    const ushort* pb0 = wt + (size_t)(bn0 + nw + lr) * F_ + lk;

    f32x4 acc0 = {}, acc1 = {};

    #pragma unroll 4
    for (int kk = 0; kk < F_; kk += 32) {
        short8 a0 = *(const short8*)(pa0 + kk);
        short8 a1 = *(const short8*)(pa1 + kk);
        short8 b0 = *(const short8*)(pb0 + kk);
        acc0 = __builtin_amdgcn_mfma_f32_16x16x32_bf16(a0, b0, acc0, 0, 0, 0);
        acc1 = __builtin_amdgcn_mfma_f32_16x16x32_bf16(a1, b0, acc1, 0, 0, 0);
    }

    // D layout: col = l&15 (n), row = (l>>4)*4 + reg (m)
    const int n = bn0 + nw + lr;
    const int k = n >> 4, d = n & 15;
    const int mbase = bm0 + mw + (l >> 4) * 4;
    float* dst = act + (size_t)k * (B_ * D_) + d;
    #pragma unroll
    for (int r = 0; r < 4; ++r) {
        dst[(size_t)(mbase + r) * D_]      = acc0[r];
        dst[(size_t)(mbase + 16 + r) * D_] = acc1[r];
    }
}

// ---- pairwise: feats[b][k] = sum_b2 exp2(-sum_d |act[k][b][d]-act[k][b2][d]|) ----
// act is pre-scaled by log2e. 512 threads, 8 waves x 64 b2 each.
__global__ __launch_bounds__(512) void pairwise_kernel(const float* __restrict__ act,
                                                       float* __restrict__ out) {
    __shared__ float s_act[B_ * D_];   // 32 KB
    __shared__ float red[8][64];

    const int bt = blockIdx.x;    // 8
    const int k  = blockIdx.y;    // 64
    const int tid  = threadIdx.x;
    const int lane = tid & 63;
    const int wave = tid >> 6;

    const float4* src = (const float4*)(act + (size_t)k * (B_ * D_));
    #pragma unroll
    for (int i = 0; i < 4; ++i)
        ((float4*)s_act)[tid + i * 512] = src[tid + i * 512];
    __syncthreads();

    const int b = bt * 64 + lane;
    const float4* arow = (const float4*)&s_act[b * D_];
    const float4 a0 = arow[0], a1 = arow[1], a2 = arow[2], a3 = arow[3];

    float p0 = 0.0f, p1 = 0.0f;
    const int b2lo = wave * 64;
    #pragma unroll 2
    for (int b2 = b2lo; b2 < b2lo + 64; b2 += 2) {
        {
            const float4* v = (const float4*)&s_act[b2 * D_];
            const float4 v0 = v[0], v1 = v[1], v2 = v[2], v3 = v[3];
            float t0 = fabsf(a0.x - v0.x) + fabsf(a0.y - v0.y);
            float t1 = fabsf(a0.z - v0.z) + fabsf(a0.w - v0.w);
            float t2 = fabsf(a1.x - v1.x) + fabsf(a1.y - v1.y);
            float t3 = fabsf(a1.z - v1.z) + fabsf(a1.w - v1.w);
            float t4 = fabsf(a2.x - v2.x) + fabsf(a2.y - v2.y);
            float t5 = fabsf(a2.z - v2.z) + fabsf(a2.w - v2.w);
            float t6 = fabsf(a3.x - v3.x) + fabsf(a3.y - v3.y);
            float t7 = fabsf(a3.z - v3.z) + fabsf(a3.w - v3.w);
            float s = ((t0 + t1) + (t2 + t3)) + ((t4 + t5) + (t6 + t7));
            p0 += exp2_neg(s);
        }
        {
            const float4* v = (const float4*)&s_act[(b2 + 1) * D_];
            const float4 v0 = v[0], v1 = v[1], v2 = v[2], v3 = v[3];
            float t0 = fabsf(a0.x - v0.x) + fabsf(a0.y - v0.y);
            float t1 = fabsf(a0.z - v0.z) + fabsf(a0.w - v0.w);
            float t2 = fabsf(a1.x - v1.x) + fabsf(a1.y - v1.y);
            float t3 = fabsf(a1.z - v1.z) + fabsf(a1.w - v1.w);
            float t4 = fabsf(a2.x - v2.x) + fabsf(a2.y - v2.y);
            float t5 = fabsf(a2.z - v2.z) + fabsf(a2.w - v2.w);
            float t6 = fabsf(a3.x - v3.x) + fabsf(a3.y - v3.y);
            float t7 = fabsf(a3.z - v3.z) + fabsf(a3.w - v3.w);
            float s = ((t0 + t1) + (t2 + t3)) + ((t4 + t5) + (t6 + t7));
            p1 += exp2_neg(s);
        }
    }

    red[wave][lane] = p0 + p1;
    __syncthreads();
    if (wave == 0) {
        float total = 0.0f;
        #pragma unroll
        for (int i = 0; i < 8; ++i) total += red[i][lane];
        out[(size_t)b * OUTW + F_ + k] = total;
    }
}

extern "C" void kernel_launch(void* const* d_in, const int* in_sizes, int n_in,
                              void* d_out, int out_size, void* d_ws, size_t ws_size,
                              hipStream_t stream) {
    const float* x = (const float*)d_in[0];
    const float* wsrc = (const float*)d_in[1];
    float* out = (float*)d_out;

    // ws layout: xb bf16 [512][2048] (2MB) | wt bf16 [1024][2048] (4MB) | act f32 [64][512][16] (2MB)
    ushort* xb  = (ushort*)d_ws;
    ushort* wt  = (ushort*)((char*)d_ws + (size_t)2 * 1024 * 1024);
    float*  act = (float*)((char*)d_ws + (size_t)6 * 1024 * 1024);

    convert_x_kernel<<<1024, 256, 0, stream>>>(x, out, xb);
    convert_wt_kernel<<<dim3(64, 32), 256, 0, stream>>>(wsrc, wt);
    gemm_mfma_kernel<<<dim3(8, 32), 256, 0, stream>>>(xb, wt, act);
    pairwise_kernel<<<dim3(8, K_), 512, 0, stream>>>(act, out);
}